// Round 5
// baseline (79.972 us; speedup 1.0000x reference)
//
#include <hip/hip_runtime.h>

// FastGaussianModel: values[m] = sum_n exp(-0.5 * sum_d (p[m,d]-q[n,d])^2 * iv[n,d]) * w[n]
//
// Round 15: last kernel-side lever inside the single-dispatch design.
// R14 post-mortem: removing a node saved 2.1us -> per-node overhead ~2us, and
// dur_us decomposes as fill(40.5) + harness restore dispatches (~25, fixed) +
// kernel (~5-8) + node (~2). Only the kernel share is controllable.
// Changes vs R14:
//  (a) TILE_PTS 128->64 (1 pt/lane): 782 blocks -> 6.1 waves/SIMD dispatched
//      (was 3.05) and 3.05 blocks/CU (was 1.53 -> half the CUs did 2x work;
//      tail now balanced).
//  (b) build is straight-line: exactly 1 pair/lane (PPS=64), no build loop.
//  (c) sweep inner body kept at the 7-instr minimum (5 packed + 2 exp per
//      2 evals). exp2(pp)-factoring rejected: t-pp reaches +800 on this data
//      -> inf (R9 failure mode). Single dispatch, no ws, out fully written.
// Discriminator (pre-committed): ~69-71 if kernel share real; if 71.5-73.5,
// kernel is exhausted and the floor is harness-fixed -> declare ROOFLINE.

typedef float v2f __attribute__((ext_vector_type(2)));

constexpr int WAVES   = 8;
constexpr int BLOCK   = 64 * WAVES;               // 512 threads
constexpr int TILE_PTS = 64;                      // 1 contiguous point per lane
constexpr int RECF    = 16;                       // floats per pair record (64 B)
constexpr int MAXPPS  = 64;                       // LDS chunk cap
constexpr float KLN  = -0.7213475204444817f;      // -0.5 * log2(e)
constexpr float FEPS = 1e-6f;

// record layout (v2f = {gaussian 2i, gaussian 2i+1}):
// [0]=a0 [1]=a1 [2]=a2 [3]=c [4]=w [5]=b0 [6]=b1 [7]=b2

template <int PAIRS>
__device__ __forceinline__ void sweep_fast(const v2f* __restrict__ cp, int pairs,
                                           float px, float py, float pz, float pp,
                                           v2f& acc) {
    const int n = PAIRS > 0 ? PAIRS : pairs;
    #pragma unroll 4
    for (int i = 0; i < n; ++i) {
        v2f A0 = cp[0], A1 = cp[1], A2 = cp[2], C = cp[3], W = cp[4];
        cp += 8;
        v2f t = C + (v2f){pp, pp};                        // <= ~0
        t = __builtin_elementwise_fma(A2, (v2f){pz, pz}, t);
        t = __builtin_elementwise_fma(A1, (v2f){py, py}, t);
        t = __builtin_elementwise_fma(A0, (v2f){px, px}, t);
        v2f g;
        g.x = __builtin_amdgcn_exp2f(t.x);
        g.y = __builtin_amdgcn_exp2f(t.y);
        acc = __builtin_elementwise_fma(g, W, acc);
    }
}

// general per-gaussian scales fallback
template <int PAIRS>
__device__ __forceinline__ void sweep_full(const v2f* __restrict__ cp, int pairs,
                                           float px, float py, float pz,
                                           v2f& acc) {
    const int n = PAIRS > 0 ? PAIRS : pairs;
    const float xx = px * px, yy = py * py, zz = pz * pz;
    #pragma unroll 2
    for (int i = 0; i < n; ++i) {
        v2f A0 = cp[0], A1 = cp[1], A2 = cp[2], C = cp[3], W = cp[4];
        v2f B0 = cp[5], B1 = cp[6], B2 = cp[7];
        cp += 8;
        v2f t = __builtin_elementwise_fma(B0, (v2f){xx, xx}, C);
        t = __builtin_elementwise_fma(B1, (v2f){yy, yy}, t);
        t = __builtin_elementwise_fma(B2, (v2f){zz, zz}, t);
        t = __builtin_elementwise_fma(A2, (v2f){pz, pz}, t);
        t = __builtin_elementwise_fma(A1, (v2f){py, py}, t);
        t = __builtin_elementwise_fma(A0, (v2f){px, px}, t);
        v2f g;
        g.x = __builtin_amdgcn_exp2f(t.x);
        g.y = __builtin_amdgcn_exp2f(t.y);
        acc = __builtin_elementwise_fma(g, W, acc);
    }
}

template <int PAIRS>
__global__ __launch_bounds__(BLOCK) void fgm_fused(
        const float* __restrict__ points,
        const float* __restrict__ positions,
        const float* __restrict__ log_scales,
        const float* __restrict__ intensities,
        float* __restrict__ out,
        int M, int N, int pairsPerSlice, int out_n) {
    constexpr int CPAIRS = PAIRS > 0 ? PAIRS : MAXPPS;
    __shared__ __align__(16) float recs[WAVES][CPAIRS * RECF];  // 32 KB @ 64 pairs
    __shared__ float red[WAVES][TILE_PTS];                      // 2 KB

    const int lane = threadIdx.x & 63;
    const int wave = __builtin_amdgcn_readfirstlane(threadIdx.x >> 6);
    const int PPS  = PAIRS > 0 ? PAIRS : pairsPerSlice;
    const int m    = blockIdx.x * TILE_PTS + lane;      // one point per lane

    // shared-scale candidates (uniform -> scalar loads); also the pp seed
    const float r0 = KLN / (__expf(2.0f * log_scales[0]) + FEPS);
    const float r1 = KLN / (__expf(2.0f * log_scales[1]) + FEPS);
    const float r2 = KLN / (__expf(2.0f * log_scales[2]) + FEPS);

    // --- point load: 12 B/lane, lane-contiguous (wave reads 768 B)
    float px = 0.f, py = 0.f, pz = 0.f;
    if (m < M) { px = points[3*m+0]; py = points[3*m+1]; pz = points[3*m+2]; }
    const float pp = r0*px*px + r1*py*py + r2*pz*pz;    // <= 0
    v2f acc = (v2f){0.f, 0.f};

    const int sliceBase = wave * PPS;   // this wave's gaussian-pair slice
    for (int base = 0; base < PPS; base += CPAIRS) {
        const int cnt = (PPS - base < CPAIRS) ? (PPS - base) : CPAIRS;

        // --- build: one pair per lane (straight-line at PPS<=64) ---
        bool ok = true;
        if (lane < cnt) {
            const int p = lane;
            const int g = (sliceBase + base + p) * 2;    // even
            float q[6] = {0,0,0,0,0,0}, l[6] = {0,0,0,0,0,0}, w[2] = {0,0};
            bool val[2] = {g < N, g + 1 < N};
            if (val[1]) {   // both halves in range: vectorized 8B loads
                const v2f* q2 = (const v2f*)(positions  + 3 * (size_t)g);
                const v2f* l2 = (const v2f*)(log_scales + 3 * (size_t)g);
                v2f Q01 = q2[0], Q23 = q2[1], Q45 = q2[2];
                v2f L01 = l2[0], L23 = l2[1], L45 = l2[2];
                v2f W01 = *(const v2f*)(intensities + g);
                q[0]=Q01.x; q[1]=Q01.y; q[2]=Q23.x; q[3]=Q23.y; q[4]=Q45.x; q[5]=Q45.y;
                l[0]=L01.x; l[1]=L01.y; l[2]=L23.x; l[3]=L23.y; l[4]=L45.x; l[5]=L45.y;
                w[0]=W01.x; w[1]=W01.y;
            } else if (val[0]) {
                q[0]=positions[3*g+0]; q[1]=positions[3*g+1]; q[2]=positions[3*g+2];
                l[0]=log_scales[3*g+0]; l[1]=log_scales[3*g+1]; l[2]=log_scales[3*g+2];
                w[0]=intensities[g];
            }
            float va[2][8];
            #pragma unroll
            for (int h = 0; h < 2; ++h) {
                float a0=0.f,a1=0.f,a2=0.f,b0=0.f,b1=0.f,b2=0.f,c=0.f,wt=0.f;
                if (val[h]) {
                    b0 = KLN / (__expf(2.0f*l[3*h+0]) + FEPS);
                    b1 = KLN / (__expf(2.0f*l[3*h+1]) + FEPS);
                    b2 = KLN / (__expf(2.0f*l[3*h+2]) + FEPS);
                    a0 = -2.f*b0*q[3*h+0];  a1 = -2.f*b1*q[3*h+1];  a2 = -2.f*b2*q[3*h+2];
                    c  = b0*q[3*h+0]*q[3*h+0] + b1*q[3*h+1]*q[3*h+1]
                       + b2*q[3*h+2]*q[3*h+2];                        // <= 0 (K folded)
                    wt = w[h];
                    if (b0 != r0 || b1 != r1 || b2 != r2) ok = false;
                }
                // padded gaussians: a=c=0, w=0 -> t=pp<=0, g finite, g*w=0
                va[h][0]=a0; va[h][1]=a1; va[h][2]=a2; va[h][3]=c;
                va[h][4]=wt; va[h][5]=b0; va[h][6]=b1; va[h][7]=b2;
            }
            v2f* r = (v2f*)&recs[wave][p * RECF];
            #pragma unroll
            for (int k = 0; k < 8; ++k) r[k] = (v2f){va[0][k], va[1][k]};
        }
        const bool fast = __all(ok);   // wave-uniform branch select
        __syncthreads();               // records visible; all waves same trips

        const v2f* cp = (const v2f*)recs[wave];
        if (fast) sweep_fast<PAIRS>(cp, cnt, px, py, pz, pp, acc);
        else      sweep_full<PAIRS>(cp, cnt, px, py, pz, acc);
        if (base + CPAIRS < PPS) __syncthreads();   // before overwrite
    }

    // --- fan-in: 8 partial rows in LDS, then ONE coalesced store per point
    red[wave][lane] = acc.x + acc.y;
    __syncthreads();

    if (threadIdx.x < TILE_PTS) {
        int p = threadIdx.x;
        int mo = blockIdx.x * TILE_PTS + p;
        if (mo < out_n) {
            float s = 0.f;
            if (mo < M) {
                #pragma unroll
                for (int w2 = 0; w2 < WAVES; ++w2) s += red[w2][p];
            }
            out[mo] = s;    // exactly one writer per element; covers out_n
        }
    }
}

extern "C" void kernel_launch(void* const* d_in, const int* in_sizes, int n_in,
                              void* d_out, int out_size, void* d_ws, size_t ws_size,
                              hipStream_t stream) {
    const float* points      = (const float*)d_in[0];
    const float* positions   = (const float*)d_in[1];
    const float* log_scales  = (const float*)d_in[2];
    const float* intensities = (const float*)d_in[3];
    int M = in_sizes[0] / 3;
    int N = in_sizes[3];

    int Npairs = (N + 1) / 2;
    int PPS    = (Npairs + WAVES - 1) / WAVES;        // 64 @ N=1024
    int cover  = (M > out_size) ? M : out_size;       // overwrite ALL of out
    int tiles  = (cover + TILE_PTS - 1) / TILE_PTS;   // 782 @ M=50000

    dim3 grid(tiles);                                 // ONE dispatch, no ws
    if (PPS == 64) {
        fgm_fused<64><<<grid, BLOCK, 0, stream>>>(points, positions, log_scales,
                                                  intensities, (float*)d_out,
                                                  M, N, PPS, out_size);
    } else {
        fgm_fused<0><<<grid, BLOCK, 0, stream>>>(points, positions, log_scales,
                                                 intensities, (float*)d_out,
                                                 M, N, PPS, out_size);
    }
}

// Round 7
// 70.364 us; speedup vs baseline: 1.1365x; 1.1365x over previous
//
#include <hip/hip_runtime.h>

// FastGaussianModel: values[m] = sum_n exp(-0.5 * sum_d (p[m,d]-q[n,d])^2 * iv[n,d]) * w[n]
//
// Round 17 = Round 16 resubmitted verbatim (R16 hit an infra container
// failure before running; source re-audited: all loads bounds-checked,
// uniform barriers, 48KB LDS, 1024-thr block legal -> no fault vector).
//
// Design rationale (from R15's +7.7us regression, which proved the sweep is
// issue/latency-bound with ~1.4x multiplier on the issue model; R14 kernel
// ~10-12us of dur=72.3): 4 pts/lane amortizes ds-per-eval 2x (issue 0.336 ->
// 0.277 cyc/eval) while 16 waves x 32 pairs restores TLP (196 blocks x 16
// waves = 3.06 waves/SIMD, same as best-measured R14). Build halves vs R14.
// Single dispatch, no ws, out fully overwritten. Math identical to verified
// R10-R15 fast path: t = C + pp + a.p <= ~0 inside exp2.
// Pre-committed: predict 69-71; if >=71.5 or regression, the design is
// issue-bound on a ~60us harness-fixed floor -> declare ROOFLINE next round.

typedef float v2f __attribute__((ext_vector_type(2)));

constexpr int WAVES        = 16;
constexpr int BLOCK        = 64 * WAVES;          // 1024 threads
constexpr int PTS_PER_LANE = 4;
constexpr int TILE_PTS     = 256;                 // 64 lanes x 4 contiguous pts
constexpr int RECF         = 16;                  // floats per pair record (64 B)
constexpr int MAXPPS       = 32;                  // LDS chunk cap
constexpr float KLN  = -0.7213475204444817f;      // -0.5 * log2(e)
constexpr float FEPS = 1e-6f;

// record layout (v2f = {gaussian 2i, gaussian 2i+1}):
// [0]=a0 [1]=a1 [2]=a2 [3]=c [4]=w [5]=b0 [6]=b1 [7]=b2

template <int PAIRS>
__device__ __forceinline__ void sweep_fast(const v2f* __restrict__ cp, int pairs,
                                           const float* px, const float* py,
                                           const float* pz, const float* pp,
                                           v2f* acc) {
    const int n = PAIRS > 0 ? PAIRS : pairs;
    #pragma unroll 4
    for (int i = 0; i < n; ++i) {
        v2f A0 = cp[0], A1 = cp[1], A2 = cp[2], C = cp[3], W = cp[4];
        cp += 8;
        #pragma unroll
        for (int j = 0; j < PTS_PER_LANE; ++j) {
            v2f t = C + (v2f){pp[j], pp[j]};                    // <= ~0
            t = __builtin_elementwise_fma(A2, (v2f){pz[j], pz[j]}, t);
            t = __builtin_elementwise_fma(A1, (v2f){py[j], py[j]}, t);
            t = __builtin_elementwise_fma(A0, (v2f){px[j], px[j]}, t);
            v2f g;
            g.x = __builtin_amdgcn_exp2f(t.x);
            g.y = __builtin_amdgcn_exp2f(t.y);
            acc[j] = __builtin_elementwise_fma(g, W, acc[j]);
        }
    }
}

// general per-gaussian scales fallback
template <int PAIRS>
__device__ __forceinline__ void sweep_full(const v2f* __restrict__ cp, int pairs,
                                           const float* px, const float* py,
                                           const float* pz, v2f* acc) {
    const int n = PAIRS > 0 ? PAIRS : pairs;
    #pragma unroll 2
    for (int i = 0; i < n; ++i) {
        v2f A0 = cp[0], A1 = cp[1], A2 = cp[2], C = cp[3], W = cp[4];
        v2f B0 = cp[5], B1 = cp[6], B2 = cp[7];
        cp += 8;
        #pragma unroll
        for (int j = 0; j < PTS_PER_LANE; ++j) {
            v2f t = __builtin_elementwise_fma(B0, (v2f){px[j]*px[j], px[j]*px[j]}, C);
            t = __builtin_elementwise_fma(B1, (v2f){py[j]*py[j], py[j]*py[j]}, t);
            t = __builtin_elementwise_fma(B2, (v2f){pz[j]*pz[j], pz[j]*pz[j]}, t);
            t = __builtin_elementwise_fma(A2, (v2f){pz[j], pz[j]}, t);
            t = __builtin_elementwise_fma(A1, (v2f){py[j], py[j]}, t);
            t = __builtin_elementwise_fma(A0, (v2f){px[j], px[j]}, t);
            v2f g;
            g.x = __builtin_amdgcn_exp2f(t.x);
            g.y = __builtin_amdgcn_exp2f(t.y);
            acc[j] = __builtin_elementwise_fma(g, W, acc[j]);
        }
    }
}

template <int PAIRS>
__global__ __launch_bounds__(BLOCK) void fgm_fused(
        const float* __restrict__ points,
        const float* __restrict__ positions,
        const float* __restrict__ log_scales,
        const float* __restrict__ intensities,
        float* __restrict__ out,
        int M, int N, int pairsPerSlice, int out_n) {
    constexpr int CPAIRS = PAIRS > 0 ? PAIRS : MAXPPS;
    __shared__ __align__(16) float recs[WAVES][CPAIRS * RECF];  // 32 KB @ 32 pairs
    __shared__ float red[WAVES][TILE_PTS];                      // 16 KB

    const int lane = threadIdx.x & 63;
    const int wave = __builtin_amdgcn_readfirstlane(threadIdx.x >> 6);
    const int PPS  = PAIRS > 0 ? PAIRS : pairsPerSlice;
    const int m0   = blockIdx.x * TILE_PTS + PTS_PER_LANE * lane;  // 4 contiguous pts

    // shared-scale candidates (uniform -> scalar loads); also the pp seed
    const float r0 = KLN / (__expf(2.0f * log_scales[0]) + FEPS);
    const float r1 = KLN / (__expf(2.0f * log_scales[1]) + FEPS);
    const float r2 = KLN / (__expf(2.0f * log_scales[2]) + FEPS);

    // --- point load: 48 B contiguous per lane, 16B-aligned (12*m0 % 16 == 0)
    float px[4], py[4], pz[4], pp[4];
    if (m0 + 4 <= M) {
        const float4* p4 = (const float4*)(points + 3 * (size_t)m0);
        float4 f0 = p4[0], f1 = p4[1], f2 = p4[2];
        px[0] = f0.x; py[0] = f0.y; pz[0] = f0.z;
        px[1] = f0.w; py[1] = f1.x; pz[1] = f1.y;
        px[2] = f1.z; py[2] = f1.w; pz[2] = f2.x;
        px[3] = f2.y; py[3] = f2.z; pz[3] = f2.w;
    } else {
        #pragma unroll
        for (int j = 0; j < 4; ++j) {
            int m = m0 + j;
            float x = 0.f, y = 0.f, z = 0.f;
            if (m < M) { x = points[3*m+0]; y = points[3*m+1]; z = points[3*m+2]; }
            px[j] = x; py[j] = y; pz[j] = z;
        }
    }
    v2f acc[4];
    #pragma unroll
    for (int j = 0; j < 4; ++j) {
        pp[j] = r0*px[j]*px[j] + r1*py[j]*py[j] + r2*pz[j]*pz[j];  // <= 0
        acc[j] = (v2f){0.f, 0.f};
    }

    const int sliceBase = wave * PPS;   // this wave's gaussian-pair slice
    for (int base = 0; base < PPS; base += CPAIRS) {
        const int cnt = (PPS - base < CPAIRS) ? (PPS - base) : CPAIRS;

        // --- build: one pair per lane (lane < cnt <= 32), straight-line ---
        bool ok = true;
        if (lane < cnt) {
            const int p = lane;
            const int g = (sliceBase + base + p) * 2;    // even
            float q[6] = {0,0,0,0,0,0}, l[6] = {0,0,0,0,0,0}, w[2] = {0,0};
            bool val[2] = {g < N, g + 1 < N};
            if (val[1]) {   // both halves in range: vectorized 8B loads
                const v2f* q2 = (const v2f*)(positions  + 3 * (size_t)g);
                const v2f* l2 = (const v2f*)(log_scales + 3 * (size_t)g);
                v2f Q01 = q2[0], Q23 = q2[1], Q45 = q2[2];
                v2f L01 = l2[0], L23 = l2[1], L45 = l2[2];
                v2f W01 = *(const v2f*)(intensities + g);
                q[0]=Q01.x; q[1]=Q01.y; q[2]=Q23.x; q[3]=Q23.y; q[4]=Q45.x; q[5]=Q45.y;
                l[0]=L01.x; l[1]=L01.y; l[2]=L23.x; l[3]=L23.y; l[4]=L45.x; l[5]=L45.y;
                w[0]=W01.x; w[1]=W01.y;
            } else if (val[0]) {
                q[0]=positions[3*g+0]; q[1]=positions[3*g+1]; q[2]=positions[3*g+2];
                l[0]=log_scales[3*g+0]; l[1]=log_scales[3*g+1]; l[2]=log_scales[3*g+2];
                w[0]=intensities[g];
            }
            float va[2][8];
            #pragma unroll
            for (int h = 0; h < 2; ++h) {
                float a0=0.f,a1=0.f,a2=0.f,b0=0.f,b1=0.f,b2=0.f,c=0.f,wt=0.f;
                if (val[h]) {
                    b0 = KLN / (__expf(2.0f*l[3*h+0]) + FEPS);
                    b1 = KLN / (__expf(2.0f*l[3*h+1]) + FEPS);
                    b2 = KLN / (__expf(2.0f*l[3*h+2]) + FEPS);
                    a0 = -2.f*b0*q[3*h+0];  a1 = -2.f*b1*q[3*h+1];  a2 = -2.f*b2*q[3*h+2];
                    c  = b0*q[3*h+0]*q[3*h+0] + b1*q[3*h+1]*q[3*h+1]
                       + b2*q[3*h+2]*q[3*h+2];                        // <= 0 (K folded)
                    wt = w[h];
                    if (b0 != r0 || b1 != r1 || b2 != r2) ok = false;
                }
                // padded gaussians: a=c=0, w=0 -> t=pp<=0, g finite, g*w=0
                va[h][0]=a0; va[h][1]=a1; va[h][2]=a2; va[h][3]=c;
                va[h][4]=wt; va[h][5]=b0; va[h][6]=b1; va[h][7]=b2;
            }
            v2f* r = (v2f*)&recs[wave][p * RECF];
            #pragma unroll
            for (int k = 0; k < 8; ++k) r[k] = (v2f){va[0][k], va[1][k]};
        }
        const bool fast = __all(ok);   // wave-uniform branch select (own slice)
        __syncthreads();               // records visible; all waves same trips

        const v2f* cp = (const v2f*)recs[wave];
        if (fast) sweep_fast<PAIRS>(cp, cnt, px, py, pz, pp, acc);
        else      sweep_full<PAIRS>(cp, cnt, px, py, pz, acc);
        if (base + CPAIRS < PPS) __syncthreads();   // before overwrite
    }

    // --- fan-in: 16 partial rows in LDS, then ONE coalesced store per point
    #pragma unroll
    for (int j = 0; j < 4; ++j)
        red[wave][4*lane + j] = acc[j].x + acc[j].y;   // one-time write
    __syncthreads();

    if (threadIdx.x < TILE_PTS) {
        int p = threadIdx.x;
        int mo = blockIdx.x * TILE_PTS + p;
        if (mo < out_n) {
            float s = 0.f;
            if (mo < M) {
                #pragma unroll
                for (int w2 = 0; w2 < WAVES; ++w2) s += red[w2][p];  // conflict-free
            }
            out[mo] = s;    // exactly one writer per element; covers out_n
        }
    }
}

extern "C" void kernel_launch(void* const* d_in, const int* in_sizes, int n_in,
                              void* d_out, int out_size, void* d_ws, size_t ws_size,
                              hipStream_t stream) {
    const float* points      = (const float*)d_in[0];
    const float* positions   = (const float*)d_in[1];
    const float* log_scales  = (const float*)d_in[2];
    const float* intensities = (const float*)d_in[3];
    int M = in_sizes[0] / 3;
    int N = in_sizes[3];

    int Npairs = (N + 1) / 2;
    int PPS    = (Npairs + WAVES - 1) / WAVES;        // 32 @ N=1024
    int cover  = (M > out_size) ? M : out_size;       // overwrite ALL of out
    int tiles  = (cover + TILE_PTS - 1) / TILE_PTS;   // 196 @ M=50000

    dim3 grid(tiles);                                 // ONE dispatch, no ws
    if (PPS == 32) {
        fgm_fused<32><<<grid, BLOCK, 0, stream>>>(points, positions, log_scales,
                                                  intensities, (float*)d_out,
                                                  M, N, PPS, out_size);
    } else {
        fgm_fused<0><<<grid, BLOCK, 0, stream>>>(points, positions, log_scales,
                                                 intensities, (float*)d_out,
                                                 M, N, PPS, out_size);
    }
}